// Round 8
// baseline (257.689 us; speedup 1.0000x reference)
//
#include <hip/hip_runtime.h>
#include <hip/hip_bf16.h>

typedef __hip_bfloat16 bf16;
typedef unsigned short ushort;

#define NN 100000
#define NE 1600000
#define NBKT 391      // ceil(NN/256) buckets of 256 dst nodes
#define BCAP 4608     // per-bucket capacity (mean 4092, sd 64, +8 sigma)
#define EPB 4096      // edges per count/place block
#define NP1 391       // ceil(NE/EPB)
#define NMT 6250      // NN/16 M-tiles for the MFMA GEMM

typedef __attribute__((ext_vector_type(8))) short s8v;   // 8 bf16 (4 VGPRs)
typedef __attribute__((ext_vector_type(4))) float f4v;   // MFMA C/D
typedef __attribute__((ext_vector_type(2))) float f2v;   // packed f32 (v_pk_add_f32)

// ---- flag-dispatched load/store: flag==1 -> f32 storage, 0 -> bf16 -------
__device__ __forceinline__ float ldf(const void* p, int i, int f32) {
    return f32 ? ((const float*)p)[i] : __bfloat162float(((const bf16*)p)[i]);
}
__device__ __forceinline__ void stf(void* p, int i, int f32, float v) {
    if (f32) ((float*)p)[i] = v;
    else     ((bf16*)p)[i] = __float2bfloat16(v);
}

// round-to-nearest-even float -> bf16 bits, and back
__device__ __forceinline__ ushort f2b(float f) {
    unsigned u = __builtin_bit_cast(unsigned, f);
    u += 0x7FFF + ((u >> 16) & 1);
    return (ushort)(u >> 16);
}
__device__ __forceinline__ float b2f(ushort h) {
    unsigned u = ((unsigned)h) << 16;
    return __builtin_bit_cast(float, u);
}
// bf16x2 dword -> two f32 (lo = bits<<16, hi = bits&0xffff0000)
__device__ __forceinline__ float blo(unsigned u) {
    return __builtin_bit_cast(float, u << 16);
}
__device__ __forceinline__ float bhi(unsigned u) {
    return __builtin_bit_cast(float, u & 0xffff0000u);
}
// unpack bf16x2 dword into a packed f32 pair (consumed by v_pk_add_f32)
__device__ __forceinline__ f2v up2(unsigned u) {
    f2v r; r.x = blo(u); r.y = bhi(u); return r;
}

__global__ void k_sentinel(unsigned* out) {
    if (threadIdx.x == 0 && blockIdx.x == 0) out[0] = 0x461C461Cu;
}

// ---------------- CSR build A: per-block bucket counts + dtype detect ------
__global__ void k_cnt(const unsigned* __restrict__ x, int* __restrict__ flag,
                      const int* __restrict__ dst, int* __restrict__ cnt) {
    __shared__ int hist[NBKT];
    int b = blockIdx.x, t = threadIdx.x;
    for (int i = t; i < NBKT; i += 256) hist[i] = 0;
    __syncthreads();
    int e0 = b * EPB;
#pragma unroll
    for (int k = 0; k < EPB; k += 256) {
        int e = e0 + k + t;
        if (e < NE) atomicAdd(&hist[dst[e] >> 8], 1);
    }
    __syncthreads();
    for (int i = t; i < NBKT; i += 256) cnt[b * NBKT + i] = hist[i];
    if (b == 0) {
        // dtype detect on first 2048 words of x (merged launch; reuses hist)
        int c = 0;
        for (int i = t; i < 2048; i += 256) {
            unsigned e7 = (x[i] >> 8) & 0x7F;
            c += (e7 >= 60 && e7 <= 66) ? 1 : 0;
        }
        __syncthreads();
        hist[t] = c;
        __syncthreads();
        for (int s = 128; s > 0; s >>= 1) {
            if (t < s) hist[t] += hist[t + s];
            __syncthreads();
        }
        if (t == 0) *flag = (hist[0] >= 1024) ? 0 : 1;  // 1 = float32 tensors
    }
}

// ---------------- CSR build B: per-bucket scan over blocks -----------------
// Block k reads column cnt[.][k] (strided reads, L2/L3-cached), scans,
// writes exclusive prefixes COALESCED to prefT[k][.] and the bucket total.
__global__ void k_colscan(const int* __restrict__ cnt, int* __restrict__ prefT,
                          int* __restrict__ btot) {
    __shared__ int s[512];
    int k = blockIdx.x, t = threadIdx.x;
    int v = (t < NP1) ? cnt[t * NBKT + k] : 0;
    s[t] = v;
    __syncthreads();
    for (int d = 1; d < 512; d <<= 1) {
        int add = (t >= d) ? s[t - d] : 0;
        __syncthreads();
        s[t] += add;
        __syncthreads();
    }
    if (t < NP1) prefT[k * NP1 + t] = s[t] - v;   // exclusive over blocks
    if (t == 511) btot[k] = s[511];
}

// ---------------- CSR build C: deterministic place into buckets ------------
// No global atomics: slot = prefT[k][b] + LDS cursor. Writes are ~10-word
// contiguous runs per bucket (vs 16x-amplified random 4B stores in r3).
__global__ void k_place(const int* __restrict__ src, const int* __restrict__ dst,
                        const int* __restrict__ prefT, unsigned* __restrict__ bbuf) {
    __shared__ int base[NBKT];
    __shared__ int lcur[NBKT];
    int b = blockIdx.x, t = threadIdx.x;
    for (int i = t; i < NBKT; i += 256) {
        base[i] = prefT[i * NP1 + b];
        lcur[i] = 0;
    }
    __syncthreads();
    int e0 = b * EPB;
#pragma unroll
    for (int k = 0; k < EPB; k += 256) {
        int e = e0 + k + t;
        if (e < NE) {
            int d = dst[e];
            int kb = d >> 8;
            int lp = atomicAdd(&lcur[kb], 1);
            bbuf[kb * BCAP + base[kb] + lp] = ((unsigned)src[e] << 8) | (unsigned)(d & 255);
        }
    }
}

// ---------------- CSR build D: LDS counting-sort per bucket ----------------
// Emits csr_off (BYTE offsets src*128) coalesced, plus rowptr and dis.
// Bucket base g0 = sum(btot[0..b-1]) is computed locally (replaces the
// former single-block scan kernel -- one fewer launch).
__global__ void k_pass2(const unsigned* __restrict__ bbuf, const int* __restrict__ btot,
                        int* __restrict__ rowptr, float* __restrict__ dis,
                        int* __restrict__ csr_off) {
    __shared__ unsigned vals[BCAP];
    __shared__ int lout[BCAP];
    __shared__ int fh[256], fx[256], fc[256];
    int b = blockIdx.x, t = threadIdx.x;
    // ---- local bucket base: reduce btot[0..b-1] (<=2 loads/thread) ----
    int part = 0;
    for (int i = t; i < b; i += 256) part += btot[i];
    fh[t] = part;
    __syncthreads();
    for (int s = 128; s > 0; s >>= 1) {
        if (t < s) fh[t] += fh[t + s];
        __syncthreads();
    }
    int g0 = fh[0];
    int cntb = btot[b];
    if (b == 0 && t == 0) rowptr[NN] = NE;
    __syncthreads();
    const unsigned* in = bbuf + b * BCAP;
    fh[t] = 0;
    __syncthreads();
    for (int i = t; i < cntb; i += 256) {
        unsigned v = in[i];
        vals[i] = v;
        atomicAdd(&fh[v & 255], 1);
    }
    __syncthreads();
    fx[t] = fh[t];
    __syncthreads();
    for (int d = 1; d < 256; d <<= 1) {
        int add = (t >= d) ? fx[t - d] : 0;
        __syncthreads();
        fx[t] += add;
        __syncthreads();
    }
    int n = b * 256 + t;
    int ex = fx[t] - fh[t];     // exclusive within bucket
    fc[t] = ex;
    if (n < NN) {
        rowptr[n] = g0 + ex;
        dis[n] = rsqrtf(1.0f + (float)fh[t]);
    }
    __syncthreads();
    for (int i = t; i < cntb; i += 256) {
        unsigned v = vals[i];
        int p = atomicAdd(&fc[v & 255], 1);
        lout[p] = (int)((v >> 8) << 7);   // src*128 = byte offset of bf16 row
    }
    __syncthreads();
    for (int i = t; i < cntb; i += 256) csr_off[g0 + i] = lout[i];
}

// ---------------- MFMA GEMM: C[N,64] = dis[row] * (A[N,64] @ W[64,64]) ----
__global__ void __launch_bounds__(256) k_gemm_mfma(
        const void* __restrict__ A, int aBase, const void* __restrict__ W,
        bf16* __restrict__ C, const float* __restrict__ dis,
        const int* __restrict__ flag) {
    int f32 = *flag;
    int t = threadIdx.x;
    // zero pad row NN (the aggregate's ZOFF target) once per GEMM launch
    if (blockIdx.x == 0 && t < 64) ((ushort*)C)[NN * 64 + t] = 0;
    int lane = t & 63;
    int w = t >> 6;
    int m = lane & 15, q = lane >> 4;

    s8v bh[2][4], bl[2][4];
#pragma unroll
    for (int st = 0; st < 2; st++)
#pragma unroll
        for (int nt = 0; nt < 4; nt++)
#pragma unroll
            for (int j = 0; j < 8; j++) {
                int k = st * 32 + q * 8 + j;
                float wv = ldf(W, k * 64 + nt * 16 + m, f32);
                ushort h = f2b(wv);
                bh[st][nt][j] = (short)h;
                bl[st][nt][j] = (short)f2b(wv - b2f(h));
            }

    ushort* Cu = (ushort*)C;
    int gw = blockIdx.x * 4 + w;
    int nw = gridDim.x * 4;
    for (int mt = gw; mt < NMT; mt += nw) {
        int row = mt * 16 + m;
        s8v ah[2], al[2];
        if (f32) {
            const float* ap = (const float*)A + aBase + row * 64 + q * 8;
#pragma unroll
            for (int st = 0; st < 2; st++)
#pragma unroll
                for (int j = 0; j < 8; j++) {
                    float v = ap[st * 32 + j];
                    ushort h = f2b(v);
                    ah[st][j] = (short)h;
                    al[st][j] = (short)f2b(v - b2f(h));
                }
        } else {
            const short* ap = (const short*)A + aBase + row * 64 + q * 8;
            ah[0] = *(const s8v*)(ap);
            ah[1] = *(const s8v*)(ap + 32);
        }
        float dr[4];
#pragma unroll
        for (int r = 0; r < 4; r++) dr[r] = dis[mt * 16 + q * 4 + r];
#pragma unroll
        for (int nt = 0; nt < 4; nt++) {
            f4v acc = {0.f, 0.f, 0.f, 0.f};
#pragma unroll
            for (int st = 0; st < 2; st++)
                acc = __builtin_amdgcn_mfma_f32_16x16x32_bf16(ah[st], bh[st][nt], acc, 0, 0, 0);
            if (f32) {
#pragma unroll
                for (int st = 0; st < 2; st++) {
                    acc = __builtin_amdgcn_mfma_f32_16x16x32_bf16(ah[st], bl[st][nt], acc, 0, 0, 0);
                    acc = __builtin_amdgcn_mfma_f32_16x16x32_bf16(al[st], bh[st][nt], acc, 0, 0, 0);
                }
            }
            int col = nt * 16 + m;
#pragma unroll
            for (int r = 0; r < 4; r++) {
                int rr = mt * 16 + q * 4 + r;
                Cu[rr * 64 + col] = f2b(dr[r] * acc[r]);
            }
        }
    }
}

// ---------------- fused aggregate + bias + relu (+ optional head) ----------
// hs holds PRE-SCALED rows dis[s]*h[s] (bf16). One WAVE per node, persistent
// blocks. Lanes: 4 row-slots (q) x 16 feature-quads (m); uint2 gathers.
// MODE==1 computes log_softmax(h2 @ W3 + b3) fully in-register. r7 lesson:
// the LDS W3 tile was a 16-way bank conflict (917K conflict cycles) -- each
// lane's W3 slice is FIXED (rows m*4..m*4+3, cols q*4..q*4+3), so it now
// lives in 16 registers loaded once before the node loop. expf/logf (libm
// sequences) replaced with __expf/__logf (hw v_exp/v_log; bf16-level
// precision). MODE==0 gates the whole epilogue on q==0 as in r5.
template<int MODE>
__global__ void __launch_bounds__(256, 8) k_aggregate(
        const bf16* __restrict__ hs, void* hout, int hoBase,
        const float* __restrict__ dis,
        const int* __restrict__ rowptr,
        const int* __restrict__ csr_off,
        const void* __restrict__ bias,
        const int* __restrict__ flag,
        const void* __restrict__ W3, const void* __restrict__ b3,
        void* __restrict__ lgout) {
    int f32 = *flag;
    int t = threadIdx.x;
    int l = t & 63;
    int q = l >> 4;           // row slot 0..3 (also head class-quad)
    int m = l & 15;           // feature quad: features 4m..4m+3
    int fb = m * 8;           // byte offset of feature quad within 128B row
    const char* hb = (const char*)hs;
    float b0 = ldf(bias, m * 4 + 0, f32);
    float b1v = ldf(bias, m * 4 + 1, f32);
    float b2v = ldf(bias, m * 4 + 2, f32);
    float b3v = ldf(bias, m * 4 + 3, f32);
    float hb3[4];
    float w3r[4][4];          // per-lane W3 slice: [feat i][class j]
    if constexpr (MODE == 1) {
#pragma unroll
        for (int i = 0; i < 4; i++)
#pragma unroll
            for (int j2 = 0; j2 < 4; j2++)
                w3r[i][j2] = ldf(W3, (m * 4 + i) * 16 + q * 4 + j2, f32);
#pragma unroll
        for (int j2 = 0; j2 < 4; j2++) hb3[j2] = ldf(b3, q * 4 + j2, f32);
    }
    const int Z = NN * 128;   // zero-row byte offset
    int wid = blockIdx.x * 4 + (t >> 6);
    int nwav = gridDim.x * 4;
    for (int n = wid; n < NN; n += nwav) {
        int r0 = rowptr[n], r1 = rowptr[n + 1];
        f2v a01 = {0.f, 0.f}, a23 = {0.f, 0.f};
        int j = r0;
        // full groups: 16 edges, 4 gathers, zero per-edge branching
        for (; j + 16 <= r1; j += 16) {
            int o0 = csr_off[j + q];
            int o1 = csr_off[j + 4 + q];
            int o2 = csr_off[j + 8 + q];
            int o3 = csr_off[j + 12 + q];
            uint2 v0 = *(const uint2*)(hb + o0 + fb);
            uint2 v1 = *(const uint2*)(hb + o1 + fb);
            uint2 v2 = *(const uint2*)(hb + o2 + fb);
            uint2 v3 = *(const uint2*)(hb + o3 + fb);
            a01 += up2(v0.x); a23 += up2(v0.y);
            a01 += up2(v1.x); a23 += up2(v1.y);
            a01 += up2(v2.x); a23 += up2(v2.y);
            a01 += up2(v3.x); a23 += up2(v3.y);
        }
        // tail group: dead slots redirect to the zero row (csr_off reads up
        // to NE+14 land in the allocated bufA region, values discarded)
        if (j < r1) {
            int i0 = j + q, i1 = j + 4 + q, i2 = j + 8 + q, i3 = j + 12 + q;
            int o0 = csr_off[i0]; o0 = (i0 < r1) ? o0 : Z;
            int o1 = csr_off[i1]; o1 = (i1 < r1) ? o1 : Z;
            int o2 = csr_off[i2]; o2 = (i2 < r1) ? o2 : Z;
            int o3 = csr_off[i3]; o3 = (i3 < r1) ? o3 : Z;
            uint2 v0 = *(const uint2*)(hb + o0 + fb);
            uint2 v1 = *(const uint2*)(hb + o1 + fb);
            uint2 v2 = *(const uint2*)(hb + o2 + fb);
            uint2 v3 = *(const uint2*)(hb + o3 + fb);
            a01 += up2(v0.x); a23 += up2(v0.y);
            a01 += up2(v1.x); a23 += up2(v1.y);
            a01 += up2(v2.x); a23 += up2(v2.y);
            a01 += up2(v3.x); a23 += up2(v3.y);
        }
        // reduce across the 4 row slots (q): xor-32 then xor-16
        float a0 = a01.x, a1 = a01.y, a2 = a23.x, a3 = a23.y;
        a0 += __shfl_xor(a0, 32); a1 += __shfl_xor(a1, 32);
        a2 += __shfl_xor(a2, 32); a3 += __shfl_xor(a3, 32);
        a0 += __shfl_xor(a0, 16); a1 += __shfl_xor(a1, 16);
        a2 += __shfl_xor(a2, 16); a3 += __shfl_xor(a3, 16);
        if constexpr (MODE == 0) {
            if (q == 0) {
                uint2 sv = *(const uint2*)(hb + n * 128 + fb);  // self row
                float dn = dis[n];
                float o0 = fmaxf(dn * (a0 + blo(sv.x)) + b0, 0.f);
                float o1 = fmaxf(dn * (a1 + bhi(sv.x)) + b1v, 0.f);
                float o2 = fmaxf(dn * (a2 + blo(sv.y)) + b2v, 0.f);
                float o3 = fmaxf(dn * (a3 + bhi(sv.y)) + b3v, 0.f);
                if (f32) {
                    float4 ov = {o0, o1, o2, o3};
                    *(float4*)((float*)hout + hoBase + n * 64 + m * 4) = ov;
                } else {
                    unsigned w0 = (unsigned)f2b(o0) | ((unsigned)f2b(o1) << 16);
                    unsigned w1 = (unsigned)f2b(o2) | ((unsigned)f2b(o3) << 16);
                    uint2 wv; wv.x = w0; wv.y = w1;
                    *(uint2*)((ushort*)hout + hoBase + n * 64 + m * 4) = wv;
                }
            }
        } else {
            // ALL lanes finish the row (head needs every lane's o0..o3);
            // the self-row gather is quad-replicated -> same cache line.
            uint2 sv = *(const uint2*)(hb + n * 128 + fb);
            float dn = dis[n];
            float o0 = fmaxf(dn * (a0 + blo(sv.x)) + b0, 0.f);
            float o1 = fmaxf(dn * (a1 + bhi(sv.x)) + b1v, 0.f);
            float o2 = fmaxf(dn * (a2 + blo(sv.y)) + b2v, 0.f);
            float o3 = fmaxf(dn * (a3 + bhi(sv.y)) + b3v, 0.f);
            if (q == 0) {
                if (f32) {
                    float4 ov = {o0, o1, o2, o3};
                    *(float4*)((float*)hout + hoBase + n * 64 + m * 4) = ov;
                } else {
                    unsigned w0 = (unsigned)f2b(o0) | ((unsigned)f2b(o1) << 16);
                    unsigned w1 = (unsigned)f2b(o2) | ((unsigned)f2b(o3) << 16);
                    uint2 wv; wv.x = w0; wv.y = w1;
                    *(uint2*)((ushort*)hout + hoBase + n * 64 + m * 4) = wv;
                }
            }
            // head partials: this lane's 4 feats x its quad's 4 classes,
            // W3 slice in registers (r7's LDS tile was a 16-way conflict)
            float z0, z1, z2, z3;
            z0 = o0 * w3r[0][0]; z1 = o0 * w3r[0][1];
            z2 = o0 * w3r[0][2]; z3 = o0 * w3r[0][3];
            z0 += o1 * w3r[1][0]; z1 += o1 * w3r[1][1];
            z2 += o1 * w3r[1][2]; z3 += o1 * w3r[1][3];
            z0 += o2 * w3r[2][0]; z1 += o2 * w3r[2][1];
            z2 += o2 * w3r[2][2]; z3 += o2 * w3r[2][3];
            z0 += o3 * w3r[3][0]; z1 += o3 * w3r[3][1];
            z2 += o3 * w3r[3][2]; z3 += o3 * w3r[3][3];
            // sum over the 16 m-lanes (bits 0-3)
#pragma unroll
            for (int msk = 1; msk <= 8; msk <<= 1) {
                z0 += __shfl_xor(z0, msk); z1 += __shfl_xor(z1, msk);
                z2 += __shfl_xor(z2, msk); z3 += __shfl_xor(z3, msk);
            }
            z0 += hb3[0]; z1 += hb3[1]; z2 += hb3[2]; z3 += hb3[3];
            // log_softmax across 16 classes (quads live on lane bits 4-5)
            float M = fmaxf(fmaxf(z0, z1), fmaxf(z2, z3));
            M = fmaxf(M, __shfl_xor(M, 16));
            M = fmaxf(M, __shfl_xor(M, 32));
            float es = __expf(z0 - M) + __expf(z1 - M)
                     + __expf(z2 - M) + __expf(z3 - M);
            es += __shfl_xor(es, 16);
            es += __shfl_xor(es, 32);
            float ls = __logf(es) + M;
            if (m == 0) {
                if (f32) {
                    float4 ov = {z0 - ls, z1 - ls, z2 - ls, z3 - ls};
                    *(float4*)((float*)lgout + n * 16 + q * 4) = ov;
                } else {
                    unsigned p0 = (unsigned)f2b(z0 - ls) | ((unsigned)f2b(z1 - ls) << 16);
                    unsigned p1 = (unsigned)f2b(z2 - ls) | ((unsigned)f2b(z3 - ls) << 16);
                    uint2 pv; pv.x = p0; pv.y = p1;
                    *(uint2*)((ushort*)lgout + n * 16 + q * 4) = pv;
                }
            }
        }
    }
}

extern "C" void kernel_launch(void* const* d_in, const int* in_sizes, int n_in,
                              void* d_out, int out_size, void* d_ws, size_t ws_size,
                              hipStream_t stream) {
    const void* x  = d_in[0];
    const int* ei  = (const int*)d_in[1];
    const void* W1 = d_in[2];
    const void* b1 = d_in[3];
    const void* W2 = d_in[4];
    const void* b2 = d_in[5];
    const void* W3 = d_in[6];
    const void* b3 = d_in[7];

    // ws layout (4B words):
    //   0       : flag (256)
    //   256     : dis (102400)
    //   102656  : rowptr (102400, NN+1 used)
    //   205568  : btot (512, NBKT used)
    //   207104  : csr_off (NE)  -- byte offsets src*128
    //   1807104 : union { [bbuf u32[NBKT*BCAP]=1801728 | cnt 153088 | prefT 153088]
    //                     (CSR build, dead before GEMM) |
    //                     bufA bf16[(NN+1)*64] = 3200032 w }
    //             bufA row NN (bytes 12.8e6..12.8e6+128) is the zero pad row.
    const size_t NEEDED = (size_t)(1807104 + 3203072) * 4;  // ~20.05 MB (unchanged)
    if (ws_size < NEEDED) {
        k_sentinel<<<1, 64, 0, stream>>>((unsigned*)d_out);
        return;
    }
    int*      flag    = (int*)d_ws;
    float*    dis     = (float*)d_ws + 256;
    int*      rowptr  = (int*)d_ws + 102656;
    int*      btot    = (int*)d_ws + 205568;
    int*      csr_off = (int*)d_ws + 207104;
    unsigned* bbuf    = (unsigned*)((int*)d_ws + 1807104);
    int*      cnt     = (int*)d_ws + 1807104 + NBKT * BCAP;          // 3608832
    int*      prefT   = cnt + 153088;                                 // 3761920
    bf16*     bufA    = (bf16*)bbuf;   // overwrites CSR scratch after pass2

    const int* srcp = ei;
    const int* dstp = ei + NE;
    const int HB = NN * 16;   // h region starts at element NN*16 of d_out

    // ---- CSR build: count+detect -> column scan -> place -> sort ----------
    k_cnt<<<NP1, 256, 0, stream>>>((const unsigned*)x, flag, dstp, cnt);
    k_colscan<<<NBKT, 512, 0, stream>>>(cnt, prefT, btot);
    k_place<<<NP1, 256, 0, stream>>>(srcp, dstp, prefT, bbuf);
    k_pass2<<<NBKT, 256, 0, stream>>>(bbuf, btot, rowptr, dis, csr_off);

    // ---- layer 1: h1 = relu(Agg(x @ W1) + b1) ----
    k_gemm_mfma<<<512, 256, 0, stream>>>(x, 0, W1, bufA, dis, flag);
    k_aggregate<0><<<2048, 256, 0, stream>>>(bufA, d_out, HB, dis, rowptr,
                                             csr_off, b1, flag,
                                             nullptr, nullptr, nullptr);

    // ---- layer 2: h2 = relu(Agg(h1 @ W2) + b2), head fused ----
    k_gemm_mfma<<<512, 256, 0, stream>>>(d_out, HB, W2, bufA, dis, flag);
    k_aggregate<1><<<2048, 256, 0, stream>>>(bufA, d_out, HB, dis, rowptr,
                                             csr_off, b2, flag,
                                             W3, b3, d_out);
}